// Round 6
// baseline (5701.201 us; speedup 1.0000x reference)
//
#include <hip/hip_runtime.h>
#include <cstddef>
#include <cstdint>

// ---------------- problem dims ----------------
#define T_ 32
#define A_ 32
#define F_ 4
#define E_ 256
#define FE_ 1024
#define H_ 768
#define H2_ 1536
#define G4_ 3072     // 4*H
#define G8_ 6144     // 4*H2
#define DTOK_ 256
#define DDEC_ 1280
#define SEQ_ 1024    // T*A

// ---------------- ws layout (float offsets) ----------------
constexpr size_t OFF_PACKED  = 0;                          // 1024*1024
constexpr size_t OFF_XF      = OFF_PACKED + 1024ull*1024;  // 1024*3072 (swizzled)
constexpr size_t OFF_XB      = OFF_XF + 1024ull*3072;
constexpr size_t OFF_XD      = OFF_XB + 1024ull*3072;      // 32*6144 (swizzled)
constexpr size_t OFF_XDIN    = OFF_XD + 32*6144;           // 32*1280
constexpr size_t OFF_ENC     = OFF_XDIN + 32*1280;         // 1024*1536
constexpr size_t OFF_HN      = OFF_ENC + 1024ull*1536;     // 32*1536
constexpr size_t OFF_AMAT    = OFF_HN + 32*1536;           // 32*1536
constexpr size_t OFF_C0      = OFF_AMAT + 32*1536;         // 1536
// sync + exchange region (memset each launch)
constexpr size_t OFF_SYNC    = OFF_C0 + 1536;              // 16 ints
constexpr size_t OFF_PAIRS_F = OFF_SYNC + 16;              // fast  [dir][par][768] u64 = 6144 f
constexpr size_t OFF_PAIRS_M = OFF_PAIRS_F + 6144;         // mirror same layout
constexpr size_t OFF_PAIRS_D = OFF_PAIRS_M + 6144;         // dec [par][1536] u64 = 6144 f
constexpr size_t MEMSET_BYTES = (16 + 6144 * 3) * 4;       // 73792

__device__ __forceinline__ float sigf(float x) { return 1.f / (1.f + __expf(-x)); }

// L1-bypass load (reads own-XCD L2 copy; CDNA L1 is write-through so plain
// stores from any CU on this XCD are visible here).
__device__ __forceinline__ unsigned long long ld_sc0(const unsigned long long* p) {
    unsigned long long r;
    asm volatile("global_load_dwordx2 %0, %1, off sc0\n\ts_waitcnt vmcnt(0)"
                 : "=v"(r) : "v"(p) : "memory");
    return r;
}
__device__ __forceinline__ void st_plain(unsigned long long* p, unsigned long long v) {
    asm volatile("global_store_dwordx2 %0, %1, off" :: "v"(p), "v"(v) : "memory");
}
__device__ __forceinline__ unsigned long long ld_agent(const unsigned long long* p) {
    return __hip_atomic_load(p, __ATOMIC_RELAXED, __HIP_MEMORY_SCOPE_AGENT);
}
__device__ __forceinline__ void st_agent(unsigned long long* p, unsigned long long v) {
    __hip_atomic_store(p, v, __ATOMIC_RELAXED, __HIP_MEMORY_SCOPE_AGENT);
}

// ---------------- embed + decoder-input gather ----------------
__global__ void embed_k(const int* __restrict__ lattice, const int* __restrict__ inputs,
                        const int* __restrict__ gold, const int* __restrict__ sos,
                        const float* __restrict__ emb, const float* __restrict__ tok_emb,
                        float* __restrict__ packed, float* __restrict__ xdec_in) {
    int b = blockIdx.x, tid = threadIdx.x;
    if (b < SEQ_) {
        #pragma unroll
        for (int f = 0; f < F_; ++f) {
            int vid = lattice[b * F_ + f];
            packed[(size_t)b * FE_ + f * E_ + tid] = emb[(size_t)vid * E_ + tid];
        }
    } else {
        int t = b - SEQ_;  // 0..31
        for (int j = tid; j < DDEC_; j += 256) {
            float v;
            if (j < FE_) {
                int f = j >> 8, e2 = j & 255;
                int vid = (t == 0) ? sos[f]
                                   : lattice[(((t - 1) * A_) + gold[t - 1]) * F_ + f];
                v = emb[(size_t)vid * E_ + e2];
            } else {
                v = tok_emb[(size_t)inputs[t] * DTOK_ + (j - FE_)];
            }
            xdec_in[(size_t)t * DDEC_ + j] = v;
        }
    }
}

// ---------------- fp32 tiled GEMM: C[M,N] = A[M,K] @ B[K,N] + bias ----------------
// swh != 0: gate-interleaved output swizzle for the LSTM consumers:
//   n = q*swh + j  -> n' = (j/dbs)*(4*dbs) + (j%dbs)*4 + q.  (q tile-uniform: swh%BN==0)
#define BM 128
#define BN 128
#define BK 8
__device__ __forceinline__ void gemm_body(
    const float* __restrict__ A, const float* __restrict__ B,
    const float* __restrict__ bias, float* __restrict__ C,
    int M, int N, int K, int n0, int m0, int swh, int dbs) {
    __shared__ float As[BK][BM + 4];
    __shared__ float Bs[BK][BN + 4];
    int tid = threadIdx.x;
    int tx = tid & 15, ty = tid >> 4;
    int lam = tid >> 1, lak = (tid & 1) * 4;
    int lbk = tid >> 5, lbn = (tid & 31) * 4;
    float acc[8][8] = {};
    for (int k0 = 0; k0 < K; k0 += BK) {
        float4 av = make_float4(0.f, 0.f, 0.f, 0.f);
        if (m0 + lam < M)
            av = *(const float4*)(A + (size_t)(m0 + lam) * K + k0 + lak);
        float4 bv = *(const float4*)(B + (size_t)(k0 + lbk) * N + n0 + lbn);
        __syncthreads();
        As[lak + 0][lam] = av.x; As[lak + 1][lam] = av.y;
        As[lak + 2][lam] = av.z; As[lak + 3][lam] = av.w;
        *(float4*)&Bs[lbk][lbn] = bv;
        __syncthreads();
        #pragma unroll
        for (int kk = 0; kk < BK; ++kk) {
            float a[8], b[8];
            *(float4*)&a[0] = *(const float4*)&As[kk][ty * 8];
            *(float4*)&a[4] = *(const float4*)&As[kk][ty * 8 + 4];
            *(float4*)&b[0] = *(const float4*)&Bs[kk][tx * 8];
            *(float4*)&b[4] = *(const float4*)&Bs[kk][tx * 8 + 4];
            #pragma unroll
            for (int i = 0; i < 8; ++i)
                #pragma unroll
                for (int j = 0; j < 8; ++j)
                    acc[i][j] += a[i] * b[j];
        }
    }
    int qg = 0, jb = 0;
    if (swh) { qg = n0 / swh; jb = n0 - qg * swh; }
    #pragma unroll
    for (int i = 0; i < 8; ++i) {
        int m = m0 + ty * 8 + i;
        if (m >= M) break;
        #pragma unroll
        for (int j = 0; j < 8; ++j) {
            int n = n0 + tx * 8 + j;
            float bb = bias ? bias[n] : 0.f;
            float v = acc[i][j] + bb;
            if (swh) {
                int jc = jb + tx * 8 + j;
                n = (jc / dbs) * (4 * dbs) + (jc % dbs) * 4 + qg;
            }
            C[(size_t)m * N + n] = v;
        }
    }
}

__global__ __launch_bounds__(256) void gemm_bias_k(
    const float* __restrict__ A, const float* __restrict__ B,
    const float* __restrict__ bias, float* __restrict__ C,
    int M, int N, int K, int swh, int dbs) {
    gemm_body(A, B, bias, C, M, N, K, blockIdx.x * BN, blockIdx.y * BM, swh, dbs);
}

__global__ __launch_bounds__(256) void gemm_bias2_k(
    const float* __restrict__ A,
    const float* __restrict__ B0, const float* __restrict__ bias0, float* __restrict__ C0,
    const float* __restrict__ B1, const float* __restrict__ bias1, float* __restrict__ C1,
    int M, int N, int K, int swh, int dbs) {
    const float* B = blockIdx.z ? B1 : B0;
    const float* bias = blockIdx.z ? bias1 : bias0;
    float* C = blockIdx.z ? C1 : C0;
    gemm_body(A, B, bias, C, M, N, K, blockIdx.x * BN, blockIdx.y * BM, swh, dbs);
}

// ---------------- persistent encoder LSTM body ----------------
// 32 blocks/dir; block owns 24 dims; wave w owns local dims {2w,2w+1};
// lane = 64-way K-split (12 h/lane, 96 weight regs). FAST: exchange via
// own-XCD L2 (plain store + sc0 load) with agent-scope mirror fallback.
// SLOW: agent-scope only (MALL), any placement.
template <bool FAST>
__device__ void enc_run(int dir, int wb,
                        const float* __restrict__ X, const float* __restrict__ Wh,
                        float* __restrict__ enc,
                        unsigned long long* pf, unsigned long long* pm,
                        unsigned long long* pairsD, float* __restrict__ c0) {
    const int tid = threadIdx.x;
    const int w = tid >> 6, lane = tid & 63, g16 = lane >> 4;

    float wgt[2][3][4][4];  // [local dim][chunk][e][gate]
    #pragma unroll
    for (int l = 0; l < 2; ++l)
        #pragma unroll
        for (int i = 0; i < 3; ++i)
            #pragma unroll
            for (int e = 0; e < 4; ++e) {
                int k = 4 * lane + e + 256 * i;
                #pragma unroll
                for (int g = 0; g < 4; ++g)
                    wgt[l][i][e][g] = Wh[(size_t)k * G4_ + g * H_ + wb * 24 + 2 * w + l];
            }
    #pragma unroll
    for (int l = 0; l < 2; ++l)
        #pragma unroll
        for (int i = 0; i < 3; ++i)
            #pragma unroll
            for (int e = 0; e < 4; ++e)
                #pragma unroll
                for (int g = 0; g < 4; ++g)
                    asm volatile("" : "+v"(wgt[l][i][e][g]));

    __shared__ float h_s[2][768];
    __shared__ float part[4][104];
    float c = 0.f;

    for (int t = 0; t < SEQ_; ++t) {
        const int row = dir ? (SEQ_ - 1 - t) : t;
        float xq = 0.f;
        if (w < 2 && lane < 48)
            xq = X[(size_t)row * G4_ + wb * 96 + w * 48 + lane];

        const int par = t & 1;
        unsigned long long v;
        {
            unsigned long long* p = pf + par * 768 + tid;
            unsigned long long* q = pm + par * 768 + tid;
            int tries = 0;
            for (;;) {
                v = FAST ? ld_sc0(p) : ld_agent(q);
                if ((unsigned)(v >> 32) == (unsigned)t) break;
                if (FAST && (++tries & 15) == 15) {
                    v = ld_agent(q);
                    if ((unsigned)(v >> 32) == (unsigned)t) break;
                }
            }
        }
        h_s[par][tid] = __uint_as_float((unsigned)v);
        __syncthreads();                                   // A: h_s ready

        float a0 = 0.f, a1 = 0.f, a2 = 0.f, a3 = 0.f;      // dim 2w
        float b0 = 0.f, b1 = 0.f, b2 = 0.f, b3 = 0.f;      // dim 2w+1
        #pragma unroll
        for (int i = 0; i < 3; ++i) {
            const float4 hv = *(const float4*)&h_s[par][4 * lane + 256 * i];
            a0 += wgt[0][i][0][0] * hv.x + wgt[0][i][1][0] * hv.y + wgt[0][i][2][0] * hv.z + wgt[0][i][3][0] * hv.w;
            a1 += wgt[0][i][0][1] * hv.x + wgt[0][i][1][1] * hv.y + wgt[0][i][2][1] * hv.z + wgt[0][i][3][1] * hv.w;
            a2 += wgt[0][i][0][2] * hv.x + wgt[0][i][1][2] * hv.y + wgt[0][i][2][2] * hv.z + wgt[0][i][3][2] * hv.w;
            a3 += wgt[0][i][0][3] * hv.x + wgt[0][i][1][3] * hv.y + wgt[0][i][2][3] * hv.z + wgt[0][i][3][3] * hv.w;
            b0 += wgt[1][i][0][0] * hv.x + wgt[1][i][1][0] * hv.y + wgt[1][i][2][0] * hv.z + wgt[1][i][3][0] * hv.w;
            b1 += wgt[1][i][0][1] * hv.x + wgt[1][i][1][1] * hv.y + wgt[1][i][2][1] * hv.z + wgt[1][i][3][1] * hv.w;
            b2 += wgt[1][i][0][2] * hv.x + wgt[1][i][1][2] * hv.y + wgt[1][i][2][2] * hv.z + wgt[1][i][3][2] * hv.w;
            b3 += wgt[1][i][0][3] * hv.x + wgt[1][i][1][3] * hv.y + wgt[1][i][2][3] * hv.z + wgt[1][i][3][3] * hv.w;
        }
        #pragma unroll
        for (int m = 1; m < 16; m <<= 1) {
            a0 += __shfl_xor(a0, m); a1 += __shfl_xor(a1, m);
            a2 += __shfl_xor(a2, m); a3 += __shfl_xor(a3, m);
            b0 += __shfl_xor(b0, m); b1 += __shfl_xor(b1, m);
            b2 += __shfl_xor(b2, m); b3 += __shfl_xor(b3, m);
        }
        if ((lane & 15) == 0) {
            *(float4*)&part[g16][w * 8]     = make_float4(a0, a1, a2, a3);
            *(float4*)&part[g16][w * 8 + 4] = make_float4(b0, b1, b2, b3);
        }
        __syncthreads();                                   // B: partials ready

        if (w < 2 && lane < 48) {
            const int dd = w * 12 + (lane >> 2), q = lane & 3;
            const int po = (dd >> 1) * 8 + (dd & 1) * 4 + q;
            float s = part[0][po] + part[1][po] + part[2][po] + part[3][po] + xq;
            float tr = (q == 2) ? tanhf(s) : sigf(s);
            float s1 = __shfl_xor(tr, 1), s2 = __shfl_xor(tr, 2), s3 = __shfl_xor(tr, 3);
            float I  = (q == 0) ? tr : (q == 1) ? s1 : (q == 2) ? s2 : s3;
            float Fv = (q == 0) ? s1 : (q == 1) ? tr : (q == 2) ? s3 : s2;
            float G  = (q == 0) ? s2 : (q == 1) ? s3 : (q == 2) ? tr : s1;
            float O  = (q == 0) ? s3 : (q == 1) ? s2 : (q == 2) ? s1 : tr;
            c = Fv * c + I * G;
            float h = O * tanhf(c);
            float hc = __shfl(h, lane * 4);                // compact 12 dims -> lanes 0-11
            if (lane < 12) {
                const int idx = wb * 24 + w * 12 + lane;
                enc[(size_t)row * H2_ + dir * H_ + idx] = hc;
                unsigned long long pk = ((unsigned long long)(unsigned)(t + 1) << 32)
                                      | (unsigned long long)__float_as_uint(hc);
                const int po2 = ((t + 1) & 1) * 768 + idx;
                if (FAST) st_plain(pf + po2, pk);
                st_agent(pm + po2, pk);                    // mirror / slow path
            }
            if (t == SEQ_ - 1) {
                float cc = __shfl(c, lane * 4);
                if (lane < 12) {
                    const int idx = wb * 24 + w * 12 + lane;
                    st_agent(pairsD + (size_t)(dir * H_ + idx),
                             (unsigned long long)__float_as_uint(hc));
                    c0[dir * H_ + idx] = cc;
                }
            }
        }
    }
}

// 256 blocks (1/CU). XCD0 blocks claim fwd, XCD1 bwd; claimer #31 sets
// mode=FAST; timeout (2ms wallclock) CASes mode=SLOW. Non-participants exit.
__global__ __launch_bounds__(768, 1) void lstm_enc_k(
    const float* __restrict__ Xf, const float* __restrict__ Xb,
    const float* __restrict__ Whf, const float* __restrict__ Whb,
    float* __restrict__ enc, unsigned long long* __restrict__ pairsF,
    unsigned long long* __restrict__ pairsM, unsigned long long* __restrict__ pairsD,
    float* __restrict__ c0, int* __restrict__ sync) {
    __shared__ int sh_role[3];
    if (threadIdx.x == 0) {
        int myMode = 0, myDir = 0, mySlot = 0;
        int xcc;
        asm volatile("s_getreg_b32 %0, hwreg(HW_REG_XCC_ID)" : "=s"(xcc));
        xcc &= 7;
        int fs = -1, fd = -1;
        if (xcc == 0)      { fd = 0; fs = atomicAdd(&sync[2], 1); if (fs == 31) atomicCAS(&sync[0], 0, 1); }
        else if (xcc == 1) { fd = 1; fs = atomicAdd(&sync[3], 1); if (fs == 31) atomicCAS(&sync[1], 0, 1); }
        unsigned long long t0 = __builtin_amdgcn_s_memrealtime();
        int mF, mB;
        for (;;) {
            mF = __hip_atomic_load(&sync[0], __ATOMIC_RELAXED, __HIP_MEMORY_SCOPE_AGENT);
            mB = __hip_atomic_load(&sync[1], __ATOMIC_RELAXED, __HIP_MEMORY_SCOPE_AGENT);
            if (mF && mB) break;
            if (__builtin_amdgcn_s_memrealtime() - t0 > 200000ull) {
                if (!mF) atomicCAS(&sync[0], 0, 2);
                if (!mB) atomicCAS(&sync[1], 0, 2);
            }
            __builtin_amdgcn_s_sleep(2);
        }
        if (fd >= 0 && fs < 32 && (fd == 0 ? mF : mB) == 1) {
            myMode = 1; myDir = fd; mySlot = fs;
        } else {
            if (mF == 2) { int s = atomicAdd(&sync[4], 1); if (s < 32) { myMode = 2; myDir = 0; mySlot = s; } }
            if (myMode == 0 && mB == 2) { int s = atomicAdd(&sync[5], 1); if (s < 32) { myMode = 2; myDir = 1; mySlot = s; } }
        }
        sh_role[0] = myMode; sh_role[1] = myDir; sh_role[2] = mySlot;
    }
    __syncthreads();
    const int mode = sh_role[0];
    if (mode == 0) return;
    const int dir = sh_role[1], wb = sh_role[2];
    const float* X  = dir ? Xb : Xf;
    const float* Wh = dir ? Whb : Whf;
    unsigned long long* pf = pairsF + (size_t)dir * 1536;
    unsigned long long* pm = pairsM + (size_t)dir * 1536;
    if (mode == 1) enc_run<true >(dir, wb, X, Wh, enc, pf, pm, pairsD, c0);
    else           enc_run<false>(dir, wb, X, Wh, enc, pf, pm, pairsD, c0);
}

// ---------------- persistent decoder LSTM ----------------
// 128 blocks x 12 waves; wave w owns dim jg = wb*12+w of 1536; K=1536 ->
// 96 register weights/thread; thread polls pairs tid and tid+768 (agent scope).
__global__ __launch_bounds__(768, 1) void lstm_dec_k(
    const float* __restrict__ Xd, const float* __restrict__ Wh,
    float* __restrict__ Hn, unsigned long long* __restrict__ pairs,
    const float* __restrict__ c0) {
    const int wb = blockIdx.x;
    const int tid = threadIdx.x;
    const int w = tid >> 6, lane = tid & 63;
    const int g16 = lane >> 4;
    const int jg = wb * 12 + w;
    const int d = lane >> 2, q = lane & 3;

    float wgt[6][4][4];
    #pragma unroll
    for (int i = 0; i < 6; ++i)
        #pragma unroll
        for (int e = 0; e < 4; ++e) {
            int k = 4 * lane + e + 256 * i;
            #pragma unroll
            for (int g = 0; g < 4; ++g)
                wgt[i][e][g] = Wh[(size_t)k * G8_ + g * H2_ + jg];
        }
    #pragma unroll
    for (int i = 0; i < 6; ++i)
        #pragma unroll
        for (int e = 0; e < 4; ++e)
            #pragma unroll
            for (int g = 0; g < 4; ++g)
                asm volatile("" : "+v"(wgt[i][e][g]));

    __shared__ float h_s[2][1536];
    __shared__ float part[4][64];
    float c = (w == 0 && lane < 48) ? c0[wb * 12 + d] : 0.f;

    for (int t = 0; t < T_; ++t) {
        float xq = 0.f;
        if (w == 0 && lane < 48) xq = Xd[(size_t)t * G8_ + wb * 48 + lane];

        const int par = t & 1;
        unsigned long long* p0 = pairs + par * 1536 + tid;
        unsigned long long* p1 = p0 + 768;
        unsigned long long v0 = ld_agent(p0);
        while ((unsigned)(v0 >> 32) != (unsigned)t) v0 = ld_agent(p0);
        unsigned long long v1 = ld_agent(p1);
        while ((unsigned)(v1 >> 32) != (unsigned)t) v1 = ld_agent(p1);
        h_s[par][tid]       = __uint_as_float((unsigned)v0);
        h_s[par][tid + 768] = __uint_as_float((unsigned)v1);
        __syncthreads();                                   // A

        float a0 = 0.f, a1 = 0.f, a2 = 0.f, a3 = 0.f;
        #pragma unroll
        for (int i = 0; i < 6; ++i) {
            const float4 hv = *(const float4*)&h_s[par][4 * lane + 256 * i];
            a0 += wgt[i][0][0] * hv.x + wgt[i][1][0] * hv.y + wgt[i][2][0] * hv.z + wgt[i][3][0] * hv.w;
            a1 += wgt[i][0][1] * hv.x + wgt[i][1][1] * hv.y + wgt[i][2][1] * hv.z + wgt[i][3][1] * hv.w;
            a2 += wgt[i][0][2] * hv.x + wgt[i][1][2] * hv.y + wgt[i][2][2] * hv.z + wgt[i][3][2] * hv.w;
            a3 += wgt[i][0][3] * hv.x + wgt[i][1][3] * hv.y + wgt[i][2][3] * hv.z + wgt[i][3][3] * hv.w;
        }
        #pragma unroll
        for (int m = 1; m < 16; m <<= 1) {
            a0 += __shfl_xor(a0, m); a1 += __shfl_xor(a1, m);
            a2 += __shfl_xor(a2, m); a3 += __shfl_xor(a3, m);
        }
        if ((lane & 15) == 0)
            *(float4*)&part[g16][w * 4] = make_float4(a0, a1, a2, a3);
        __syncthreads();                                   // B

        if (w == 0) {
            float s = part[0][lane] + part[1][lane] + part[2][lane] + part[3][lane] + xq;
            float tr = (q == 2) ? tanhf(s) : sigf(s);
            float s1 = __shfl_xor(tr, 1), s2 = __shfl_xor(tr, 2), s3 = __shfl_xor(tr, 3);
            float I  = (q == 0) ? tr : (q == 1) ? s1 : (q == 2) ? s2 : s3;
            float Fv = (q == 0) ? s1 : (q == 1) ? tr : (q == 2) ? s3 : s2;
            float G  = (q == 0) ? s2 : (q == 1) ? s3 : (q == 2) ? tr : s1;
            float O  = (q == 0) ? s3 : (q == 1) ? s2 : (q == 2) ? s1 : tr;
            c = Fv * c + I * G;
            float h = O * tanhf(c);
            float hc = __shfl(h, lane * 4);
            if (lane < 12) {
                Hn[(size_t)t * H2_ + wb * 12 + lane] = hc;
                unsigned long long pk = ((unsigned long long)(unsigned)(t + 1) << 32)
                                      | (unsigned long long)__float_as_uint(hc);
                st_agent(pairs + ((t + 1) & 1) * 1536 + wb * 12 + lane, pk);
            }
        }
    }
}

// ---------------- scores: out[t][a] = Amat[t] . enc[t*32+a] ----------------
__global__ void score_k(const float* __restrict__ Amat, const float* __restrict__ enc,
                        float* __restrict__ outp) {
    int t = blockIdx.x, tid = threadIdx.x;
    __shared__ float a_s[H2_];
    for (int i = tid; i < H2_; i += 256) a_s[i] = Amat[(size_t)t * H2_ + i];
    __syncthreads();
    int aa = tid >> 3, p = tid & 7;
    const float4* e = (const float4*)(enc + (size_t)(t * A_ + aa) * H2_ + p * 192);
    const float4* ap = (const float4*)(a_s + p * 192);
    float s = 0.f;
    #pragma unroll
    for (int i = 0; i < 48; ++i) {
        float4 av = ap[i], ev = e[i];
        s += av.x * ev.x + av.y * ev.y + av.z * ev.z + av.w * ev.w;
    }
    s += __shfl_xor(s, 1); s += __shfl_xor(s, 2); s += __shfl_xor(s, 4);
    if (p == 0) outp[t * A_ + aa] = s;
}

// ---------------- host launch ----------------
extern "C" void kernel_launch(void* const* d_in, const int* in_sizes, int n_in,
                              void* d_out, int out_size, void* d_ws, size_t ws_size,
                              hipStream_t stream) {
    const int*   lattice = (const int*)d_in[0];
    const int*   inputs  = (const int*)d_in[2];
    const int*   gold    = (const int*)d_in[4];
    const int*   sos     = (const int*)d_in[5];
    const float* emb     = (const float*)d_in[6];
    const float* tok     = (const float*)d_in[7];
    const float* Wxf = (const float*)d_in[8];
    const float* Whf = (const float*)d_in[9];
    const float* bf  = (const float*)d_in[10];
    const float* Wxb = (const float*)d_in[11];
    const float* Whb = (const float*)d_in[12];
    const float* bb  = (const float*)d_in[13];
    const float* dWx = (const float*)d_in[14];
    const float* dWh = (const float*)d_in[15];
    const float* db  = (const float*)d_in[16];
    const float* aW  = (const float*)d_in[17];
    float* ws  = (float*)d_ws;
    float* out = (float*)d_out;

    float* packed = ws + OFF_PACKED;
    float* Xf     = ws + OFF_XF;
    float* Xb     = ws + OFF_XB;
    float* Xd     = ws + OFF_XD;
    float* xdin   = ws + OFF_XDIN;
    float* enc    = ws + OFF_ENC;
    float* Hn     = ws + OFF_HN;
    float* Amat   = ws + OFF_AMAT;
    float* c0     = ws + OFF_C0;
    int*   sync   = (int*)(ws + OFF_SYNC);
    unsigned long long* pairsF = (unsigned long long*)(ws + OFF_PAIRS_F);
    unsigned long long* pairsM = (unsigned long long*)(ws + OFF_PAIRS_M);
    unsigned long long* pairsD = (unsigned long long*)(ws + OFF_PAIRS_D);

    // reset sync + pair tags (graph-replay safe; {tag=0,val=0} == initial h state)
    hipMemsetAsync((char*)d_ws + OFF_SYNC * sizeof(float), 0, MEMSET_BYTES, stream);

    embed_k<<<SEQ_ + T_, 256, 0, stream>>>(lattice, inputs, gold, sos, emb, tok,
                                           packed, xdin);
    gemm_bias2_k<<<dim3(G4_ / BN, SEQ_ / BM, 2), 256, 0, stream>>>(
        packed, Wxf, bf, Xf, Wxb, bb, Xb, SEQ_, G4_, FE_, H_, 24);
    gemm_bias_k<<<dim3(G8_ / BN, 1), 256, 0, stream>>>(xdin, dWx, db, Xd,
                                                       T_, G8_, DDEC_, H2_, 12);
    lstm_enc_k<<<256, 768, 0, stream>>>(Xf, Xb, Whf, Whb, enc, pairsF, pairsM,
                                        pairsD, c0, sync);
    lstm_dec_k<<<128, 768, 0, stream>>>(Xd, dWh, Hn, pairsD, c0);
    gemm_bias_k<<<dim3(H2_ / BN, 1), 256, 0, stream>>>(Hn, aW, nullptr, Amat,
                                                       T_, H2_, H2_, 0, 1);
    score_k<<<T_, 256, 0, stream>>>(Amat, enc, out);
}

// Round 7
// 4766.297 us; speedup vs baseline: 1.1961x; 1.1961x over previous
//
#include <hip/hip_runtime.h>
#include <cstddef>
#include <cstdint>

// ---------------- problem dims ----------------
#define T_ 32
#define A_ 32
#define F_ 4
#define E_ 256
#define FE_ 1024
#define H_ 768
#define H2_ 1536
#define G4_ 3072     // 4*H
#define G8_ 6144     // 4*H2
#define DTOK_ 256
#define DDEC_ 1280
#define SEQ_ 1024    // T*A

typedef unsigned long long ull;

// ---------------- ws layout (float offsets) ----------------
constexpr size_t OFF_PACKED  = 0;                          // 1024*1024
constexpr size_t OFF_XF      = OFF_PACKED + 1024ull*1024;  // 1024*3072 (swizzled)
constexpr size_t OFF_XB      = OFF_XF + 1024ull*3072;
constexpr size_t OFF_XD      = OFF_XB + 1024ull*3072;      // 32*6144 (swizzled)
constexpr size_t OFF_XDIN    = OFF_XD + 32*6144;           // 32*1280
constexpr size_t OFF_ENC     = OFF_XDIN + 32*1280;         // 1024*1536
constexpr size_t OFF_HN      = OFF_ENC + 1024ull*1536;     // 32*1536
constexpr size_t OFF_AMAT    = OFF_HN + 32*1536;           // 32*1536
constexpr size_t OFF_C0      = OFF_AMAT + 32*1536;         // 1536 (no memset needed)
// pair buffers (memset each launch; {tag=0,val=0} == h0 state)
constexpr size_t OFF_PAIRS_F = OFF_C0 + 1536;              // fwd [par][768] u64 = 3072 f
constexpr size_t OFF_PAIRS_B = OFF_PAIRS_F + 3072;         // bwd [par][768] u64
constexpr size_t OFF_PAIRS_D = OFF_PAIRS_B + 3072;         // dec [par][1536] u64 = 6144 f
constexpr size_t MEMSET_BYTES = (3072 + 3072 + 6144) * 4;  // 49152

__device__ __forceinline__ float sigf(float x) { return 1.f / (1.f + __expf(-x)); }

__device__ __forceinline__ ull ld_agent(const ull* p) {
    return __hip_atomic_load(p, __ATOMIC_RELAXED, __HIP_MEMORY_SCOPE_AGENT);
}
__device__ __forceinline__ void st_agent(ull* p, ull v) {
    __hip_atomic_store(p, v, __ATOMIC_RELAXED, __HIP_MEMORY_SCOPE_AGENT);
}

// ---------------- embed + decoder-input gather ----------------
__global__ void embed_k(const int* __restrict__ lattice, const int* __restrict__ inputs,
                        const int* __restrict__ gold, const int* __restrict__ sos,
                        const float* __restrict__ emb, const float* __restrict__ tok_emb,
                        float* __restrict__ packed, float* __restrict__ xdec_in) {
    int b = blockIdx.x, tid = threadIdx.x;
    if (b < SEQ_) {
        #pragma unroll
        for (int f = 0; f < F_; ++f) {
            int vid = lattice[b * F_ + f];
            packed[(size_t)b * FE_ + f * E_ + tid] = emb[(size_t)vid * E_ + tid];
        }
    } else {
        int t = b - SEQ_;  // 0..31
        for (int j = tid; j < DDEC_; j += 256) {
            float v;
            if (j < FE_) {
                int f = j >> 8, e2 = j & 255;
                int vid = (t == 0) ? sos[f]
                                   : lattice[(((t - 1) * A_) + gold[t - 1]) * F_ + f];
                v = emb[(size_t)vid * E_ + e2];
            } else {
                v = tok_emb[(size_t)inputs[t] * DTOK_ + (j - FE_)];
            }
            xdec_in[(size_t)t * DDEC_ + j] = v;
        }
    }
}

// ---------------- fp32 tiled GEMM: C[M,N] = A[M,K] @ B[K,N] + bias ----------------
// swh != 0: gate-interleaved output swizzle for the LSTM consumers:
//   n = q*swh + j  -> n' = (j/dbs)*(4*dbs) + (j%dbs)*4 + q.  (q tile-uniform: swh%BN==0)
#define BM 128
#define BN 128
#define BK 8
__device__ __forceinline__ void gemm_body(
    const float* __restrict__ A, const float* __restrict__ B,
    const float* __restrict__ bias, float* __restrict__ C,
    int M, int N, int K, int n0, int m0, int swh, int dbs) {
    __shared__ float As[BK][BM + 4];
    __shared__ float Bs[BK][BN + 4];
    int tid = threadIdx.x;
    int tx = tid & 15, ty = tid >> 4;
    int lam = tid >> 1, lak = (tid & 1) * 4;
    int lbk = tid >> 5, lbn = (tid & 31) * 4;
    float acc[8][8] = {};
    for (int k0 = 0; k0 < K; k0 += BK) {
        float4 av = make_float4(0.f, 0.f, 0.f, 0.f);
        if (m0 + lam < M)
            av = *(const float4*)(A + (size_t)(m0 + lam) * K + k0 + lak);
        float4 bv = *(const float4*)(B + (size_t)(k0 + lbk) * N + n0 + lbn);
        __syncthreads();
        As[lak + 0][lam] = av.x; As[lak + 1][lam] = av.y;
        As[lak + 2][lam] = av.z; As[lak + 3][lam] = av.w;
        *(float4*)&Bs[lbk][lbn] = bv;
        __syncthreads();
        #pragma unroll
        for (int kk = 0; kk < BK; ++kk) {
            float a[8], b[8];
            *(float4*)&a[0] = *(const float4*)&As[kk][ty * 8];
            *(float4*)&a[4] = *(const float4*)&As[kk][ty * 8 + 4];
            *(float4*)&b[0] = *(const float4*)&Bs[kk][tx * 8];
            *(float4*)&b[4] = *(const float4*)&Bs[kk][tx * 8 + 4];
            #pragma unroll
            for (int i = 0; i < 8; ++i)
                #pragma unroll
                for (int j = 0; j < 8; ++j)
                    acc[i][j] += a[i] * b[j];
        }
    }
    int qg = 0, jb = 0;
    if (swh) { qg = n0 / swh; jb = n0 - qg * swh; }
    #pragma unroll
    for (int i = 0; i < 8; ++i) {
        int m = m0 + ty * 8 + i;
        if (m >= M) break;
        #pragma unroll
        for (int j = 0; j < 8; ++j) {
            int n = n0 + tx * 8 + j;
            float bb = bias ? bias[n] : 0.f;
            float v = acc[i][j] + bb;
            if (swh) {
                int jc = jb + tx * 8 + j;
                n = (jc / dbs) * (4 * dbs) + (jc % dbs) * 4 + qg;
            }
            C[(size_t)m * N + n] = v;
        }
    }
}

__global__ __launch_bounds__(256) void gemm_bias_k(
    const float* __restrict__ A, const float* __restrict__ B,
    const float* __restrict__ bias, float* __restrict__ C,
    int M, int N, int K, int swh, int dbs) {
    gemm_body(A, B, bias, C, M, N, K, blockIdx.x * BN, blockIdx.y * BM, swh, dbs);
}

__global__ __launch_bounds__(256) void gemm_bias2_k(
    const float* __restrict__ A,
    const float* __restrict__ B0, const float* __restrict__ bias0, float* __restrict__ C0,
    const float* __restrict__ B1, const float* __restrict__ bias1, float* __restrict__ C1,
    int M, int N, int K, int swh, int dbs) {
    const float* B = blockIdx.z ? B1 : B0;
    const float* bias = blockIdx.z ? bias1 : bias0;
    float* C = blockIdx.z ? C1 : C0;
    gemm_body(A, B, bias, C, M, N, K, blockIdx.x * BN, blockIdx.y * BM, swh, dbs);
}

// ---------------- persistent encoder LSTM: BOTH dirs per block ----------------
// 64 blocks x 768 threads (12 waves). Block wb owns dims [12wb..12wb+12) of BOTH
// fwd and bwd. Wave w owns dim w (both dirs); lane = 64-way K-split (12 h/lane,
// 2x48 weight regs). Poll: tid<384 polls 2 fwd pairs, tid>=384 polls 2 bwd pairs
// (proven agent-scope atomics, no sleep). All-lane butterfly tail (r3 math),
// h gathered via LDS h12, waves 0/1 publish 96B coalesced bursts (r2 pattern).
__global__ __launch_bounds__(768, 1) void lstm_enc_k(
    const float* __restrict__ Xf, const float* __restrict__ Xb,
    const float* __restrict__ Whf, const float* __restrict__ Whb,
    float* __restrict__ enc, ull* __restrict__ pF, ull* __restrict__ pB,
    ull* __restrict__ pairsD, float* __restrict__ c0) {
    const int wb = blockIdx.x;           // 0..63
    const int tid = threadIdx.x;
    const int w = tid >> 6, lane = tid & 63, q4 = lane & 3;

    float wgt[2][3][4][4];               // [dir][chunk][e][gate]
    #pragma unroll
    for (int d = 0; d < 2; ++d) {
        const float* Wh = d ? Whb : Whf;
        #pragma unroll
        for (int i = 0; i < 3; ++i)
            #pragma unroll
            for (int e = 0; e < 4; ++e) {
                int k = 4 * lane + e + 256 * i;
                #pragma unroll
                for (int g = 0; g < 4; ++g)
                    wgt[d][i][e][g] = Wh[(size_t)k * G4_ + g * H_ + wb * 12 + w];
            }
    }
    #pragma unroll
    for (int d = 0; d < 2; ++d)
        #pragma unroll
        for (int i = 0; i < 3; ++i)
            #pragma unroll
            for (int e = 0; e < 4; ++e)
                #pragma unroll
                for (int g = 0; g < 4; ++g)
                    asm volatile("" : "+v"(wgt[d][i][e][g]));

    __shared__ float hsf[2][768], hsb[2][768];
    __shared__ float xs[2][48];
    __shared__ float h12[2][12], c12[2][12];
    float cf = 0.f, cb = 0.f;

    for (int t = 0; t < SEQ_; ++t) {
        const int rowf = t, rowb = SEQ_ - 1 - t;
        // X prefetch (issued before poll; waitcnt lands at the xs store below)
        float xv = 0.f;
        if (tid < 96)
            xv = (tid < 48) ? Xf[(size_t)rowf * G4_ + wb * 48 + tid]
                            : Xb[(size_t)rowb * G4_ + wb * 48 + (tid - 48)];

        const int par = t & 1;
        if (tid < 384) {
            ull* p = pF + (size_t)par * 768 + 2 * tid;
            ull v0 = ld_agent(p), v1 = ld_agent(p + 1);
            while ((unsigned)(v0 >> 32) != (unsigned)t || (unsigned)(v1 >> 32) != (unsigned)t) {
                v0 = ld_agent(p); v1 = ld_agent(p + 1);
            }
            hsf[par][2 * tid]     = __uint_as_float((unsigned)v0);
            hsf[par][2 * tid + 1] = __uint_as_float((unsigned)v1);
        } else {
            const int u = tid - 384;
            ull* p = pB + (size_t)par * 768 + 2 * u;
            ull v0 = ld_agent(p), v1 = ld_agent(p + 1);
            while ((unsigned)(v0 >> 32) != (unsigned)t || (unsigned)(v1 >> 32) != (unsigned)t) {
                v0 = ld_agent(p); v1 = ld_agent(p + 1);
            }
            hsb[par][2 * u]     = __uint_as_float((unsigned)v0);
            hsb[par][2 * u + 1] = __uint_as_float((unsigned)v1);
        }
        if (tid < 96) xs[tid >= 48][tid < 48 ? tid : tid - 48] = xv;
        __syncthreads();                                   // A: h ready

        float a0 = 0.f, a1 = 0.f, a2 = 0.f, a3 = 0.f;      // fwd gates
        float b0 = 0.f, b1 = 0.f, b2 = 0.f, b3 = 0.f;      // bwd gates
        #pragma unroll
        for (int i = 0; i < 3; ++i) {
            const float4 hf = *(const float4*)&hsf[par][4 * lane + 256 * i];
            const float4 hb = *(const float4*)&hsb[par][4 * lane + 256 * i];
            a0 += wgt[0][i][0][0] * hf.x + wgt[0][i][1][0] * hf.y + wgt[0][i][2][0] * hf.z + wgt[0][i][3][0] * hf.w;
            a1 += wgt[0][i][0][1] * hf.x + wgt[0][i][1][1] * hf.y + wgt[0][i][2][1] * hf.z + wgt[0][i][3][1] * hf.w;
            a2 += wgt[0][i][0][2] * hf.x + wgt[0][i][1][2] * hf.y + wgt[0][i][2][2] * hf.z + wgt[0][i][3][2] * hf.w;
            a3 += wgt[0][i][0][3] * hf.x + wgt[0][i][1][3] * hf.y + wgt[0][i][2][3] * hf.z + wgt[0][i][3][3] * hf.w;
            b0 += wgt[1][i][0][0] * hb.x + wgt[1][i][1][0] * hb.y + wgt[1][i][2][0] * hb.z + wgt[1][i][3][0] * hb.w;
            b1 += wgt[1][i][0][1] * hb.x + wgt[1][i][1][1] * hb.y + wgt[1][i][2][1] * hb.z + wgt[1][i][3][1] * hb.w;
            b2 += wgt[1][i][0][2] * hb.x + wgt[1][i][1][2] * hb.y + wgt[1][i][2][2] * hb.z + wgt[1][i][3][2] * hb.w;
            b3 += wgt[1][i][0][3] * hb.x + wgt[1][i][1][3] * hb.y + wgt[1][i][2][3] * hb.z + wgt[1][i][3][3] * hb.w;
        }
        #pragma unroll
        for (int m = 1; m < 64; m <<= 1) {
            a0 += __shfl_xor(a0, m); a1 += __shfl_xor(a1, m);
            a2 += __shfl_xor(a2, m); a3 += __shfl_xor(a3, m);
            b0 += __shfl_xor(b0, m); b1 += __shfl_xor(b1, m);
            b2 += __shfl_xor(b2, m); b3 += __shfl_xor(b3, m);
        }
        // fwd tail (all lanes; values uniform after full butterfly)
        {
            float sg = ((q4 == 0) ? a0 : (q4 == 1) ? a1 : (q4 == 2) ? a2 : a3) + xs[0][w * 4 + q4];
            float tr = (q4 == 2) ? tanhf(sg) : sigf(sg);
            float I = __shfl(tr, 0), Fv = __shfl(tr, 1), G = __shfl(tr, 2), O = __shfl(tr, 3);
            cf = Fv * cf + I * G;
            float h = O * tanhf(cf);
            if (lane == 0) { h12[0][w] = h; if (t == SEQ_ - 1) c12[0][w] = cf; }
        }
        // bwd tail
        {
            float sg = ((q4 == 0) ? b0 : (q4 == 1) ? b1 : (q4 == 2) ? b2 : b3) + xs[1][w * 4 + q4];
            float tr = (q4 == 2) ? tanhf(sg) : sigf(sg);
            float I = __shfl(tr, 0), Fv = __shfl(tr, 1), G = __shfl(tr, 2), O = __shfl(tr, 3);
            cb = Fv * cb + I * G;
            float h = O * tanhf(cb);
            if (lane == 0) { h12[1][w] = h; if (t == SEQ_ - 1) c12[1][w] = cb; }
        }
        __syncthreads();                                   // B: h12 ready

        if (w < 2 && lane < 12) {                          // wave0=fwd, wave1=bwd
            const int d = w;
            const int row = d ? rowb : rowf;
            const int idx = wb * 12 + lane;
            float hv = h12[d][lane];
            ull pk = ((ull)(unsigned)(t + 1) << 32) | (ull)__float_as_uint(hv);
            st_agent((d ? pB : pF) + (size_t)((t + 1) & 1) * 768 + idx, pk);
            enc[(size_t)row * H2_ + d * H_ + idx] = hv;
            if (t == SEQ_ - 1) {
                st_agent(pairsD + (size_t)(d * H_ + idx), (ull)__float_as_uint(hv));
                c0[d * H_ + idx] = c12[d][lane];
            }
        }
    }
}

// ---------------- persistent decoder LSTM (r6 verbatim) ----------------
__global__ __launch_bounds__(768, 1) void lstm_dec_k(
    const float* __restrict__ Xd, const float* __restrict__ Wh,
    float* __restrict__ Hn, ull* __restrict__ pairs,
    const float* __restrict__ c0) {
    const int wb = blockIdx.x;
    const int tid = threadIdx.x;
    const int w = tid >> 6, lane = tid & 63;
    const int g16 = lane >> 4;
    const int jg = wb * 12 + w;
    const int d = lane >> 2, q = lane & 3;

    float wgt[6][4][4];
    #pragma unroll
    for (int i = 0; i < 6; ++i)
        #pragma unroll
        for (int e = 0; e < 4; ++e) {
            int k = 4 * lane + e + 256 * i;
            #pragma unroll
            for (int g = 0; g < 4; ++g)
                wgt[i][e][g] = Wh[(size_t)k * G8_ + g * H2_ + jg];
        }
    #pragma unroll
    for (int i = 0; i < 6; ++i)
        #pragma unroll
        for (int e = 0; e < 4; ++e)
            #pragma unroll
            for (int g = 0; g < 4; ++g)
                asm volatile("" : "+v"(wgt[i][e][g]));

    __shared__ float h_s[2][1536];
    __shared__ float part[4][64];
    float c = (w == 0 && lane < 48) ? c0[wb * 12 + d] : 0.f;

    for (int t = 0; t < T_; ++t) {
        float xq = 0.f;
        if (w == 0 && lane < 48) xq = Xd[(size_t)t * G8_ + wb * 48 + lane];

        const int par = t & 1;
        ull* p0 = pairs + (size_t)par * 1536 + tid;
        ull* p1 = p0 + 768;
        ull v0 = ld_agent(p0);
        while ((unsigned)(v0 >> 32) != (unsigned)t) v0 = ld_agent(p0);
        ull v1 = ld_agent(p1);
        while ((unsigned)(v1 >> 32) != (unsigned)t) v1 = ld_agent(p1);
        h_s[par][tid]       = __uint_as_float((unsigned)v0);
        h_s[par][tid + 768] = __uint_as_float((unsigned)v1);
        __syncthreads();                                   // A

        float a0 = 0.f, a1 = 0.f, a2 = 0.f, a3 = 0.f;
        #pragma unroll
        for (int i = 0; i < 6; ++i) {
            const float4 hv = *(const float4*)&h_s[par][4 * lane + 256 * i];
            a0 += wgt[i][0][0] * hv.x + wgt[i][1][0] * hv.y + wgt[i][2][0] * hv.z + wgt[i][3][0] * hv.w;
            a1 += wgt[i][0][1] * hv.x + wgt[i][1][1] * hv.y + wgt[i][2][1] * hv.z + wgt[i][3][1] * hv.w;
            a2 += wgt[i][0][2] * hv.x + wgt[i][1][2] * hv.y + wgt[i][2][2] * hv.z + wgt[i][3][2] * hv.w;
            a3 += wgt[i][0][3] * hv.x + wgt[i][1][3] * hv.y + wgt[i][2][3] * hv.z + wgt[i][3][3] * hv.w;
        }
        #pragma unroll
        for (int m = 1; m < 16; m <<= 1) {
            a0 += __shfl_xor(a0, m); a1 += __shfl_xor(a1, m);
            a2 += __shfl_xor(a2, m); a3 += __shfl_xor(a3, m);
        }
        if ((lane & 15) == 0)
            *(float4*)&part[g16][w * 4] = make_float4(a0, a1, a2, a3);
        __syncthreads();                                   // B

        if (w == 0) {
            float s = part[0][lane] + part[1][lane] + part[2][lane] + part[3][lane] + xq;
            float tr = (q == 2) ? tanhf(s) : sigf(s);
            float s1 = __shfl_xor(tr, 1), s2 = __shfl_xor(tr, 2), s3 = __shfl_xor(tr, 3);
            float I  = (q == 0) ? tr : (q == 1) ? s1 : (q == 2) ? s2 : s3;
            float Fv = (q == 0) ? s1 : (q == 1) ? tr : (q == 2) ? s3 : s2;
            float G  = (q == 0) ? s2 : (q == 1) ? s3 : (q == 2) ? tr : s1;
            float O  = (q == 0) ? s3 : (q == 1) ? s2 : (q == 2) ? s1 : tr;
            c = Fv * c + I * G;
            float h = O * tanhf(c);
            float hc = __shfl(h, lane * 4);
            if (lane < 12) {
                Hn[(size_t)t * H2_ + wb * 12 + lane] = hc;
                ull pk = ((ull)(unsigned)(t + 1) << 32) | (ull)__float_as_uint(hc);
                st_agent(pairs + (size_t)((t + 1) & 1) * 1536 + wb * 12 + lane, pk);
            }
        }
    }
}

// ---------------- scores: out[t][a] = Amat[t] . enc[t*32+a] ----------------
__global__ void score_k(const float* __restrict__ Amat, const float* __restrict__ enc,
                        float* __restrict__ outp) {
    int t = blockIdx.x, tid = threadIdx.x;
    __shared__ float a_s[H2_];
    for (int i = tid; i < H2_; i += 256) a_s[i] = Amat[(size_t)t * H2_ + i];
    __syncthreads();
    int aa = tid >> 3, p = tid & 7;
    const float4* e = (const float4*)(enc + (size_t)(t * A_ + aa) * H2_ + p * 192);
    const float4* ap = (const float4*)(a_s + p * 192);
    float s = 0.f;
    #pragma unroll
    for (int i = 0; i < 48; ++i) {
        float4 av = ap[i], ev = e[i];
        s += av.x * ev.x + av.y * ev.y + av.z * ev.z + av.w * ev.w;
    }
    s += __shfl_xor(s, 1); s += __shfl_xor(s, 2); s += __shfl_xor(s, 4);
    if (p == 0) outp[t * A_ + aa] = s;
}

// ---------------- host launch ----------------
extern "C" void kernel_launch(void* const* d_in, const int* in_sizes, int n_in,
                              void* d_out, int out_size, void* d_ws, size_t ws_size,
                              hipStream_t stream) {
    const int*   lattice = (const int*)d_in[0];
    const int*   inputs  = (const int*)d_in[2];
    const int*   gold    = (const int*)d_in[4];
    const int*   sos     = (const int*)d_in[5];
    const float* emb     = (const float*)d_in[6];
    const float* tok     = (const float*)d_in[7];
    const float* Wxf = (const float*)d_in[8];
    const float* Whf = (const float*)d_in[9];
    const float* bf  = (const float*)d_in[10];
    const float* Wxb = (const float*)d_in[11];
    const float* Whb = (const float*)d_in[12];
    const float* bb  = (const float*)d_in[13];
    const float* dWx = (const float*)d_in[14];
    const float* dWh = (const float*)d_in[15];
    const float* db  = (const float*)d_in[16];
    const float* aW  = (const float*)d_in[17];
    float* ws  = (float*)d_ws;
    float* out = (float*)d_out;

    float* packed = ws + OFF_PACKED;
    float* Xf     = ws + OFF_XF;
    float* Xb     = ws + OFF_XB;
    float* Xd     = ws + OFF_XD;
    float* xdin   = ws + OFF_XDIN;
    float* enc    = ws + OFF_ENC;
    float* Hn     = ws + OFF_HN;
    float* Amat   = ws + OFF_AMAT;
    float* c0     = ws + OFF_C0;
    ull* pairsF = (ull*)(ws + OFF_PAIRS_F);
    ull* pairsB = (ull*)(ws + OFF_PAIRS_B);
    ull* pairsD = (ull*)(ws + OFF_PAIRS_D);

    // reset pair tags (graph-replay safe; {tag=0,val=0} == initial h state)
    hipMemsetAsync((char*)d_ws + OFF_PAIRS_F * sizeof(float), 0, MEMSET_BYTES, stream);

    embed_k<<<SEQ_ + T_, 256, 0, stream>>>(lattice, inputs, gold, sos, emb, tok,
                                           packed, xdin);
    gemm_bias2_k<<<dim3(G4_ / BN, SEQ_ / BM, 2), 256, 0, stream>>>(
        packed, Wxf, bf, Xf, Wxb, bb, Xb, SEQ_, G4_, FE_, H_, 12);
    gemm_bias_k<<<dim3(G8_ / BN, 1), 256, 0, stream>>>(xdin, dWx, db, Xd,
                                                       T_, G8_, DDEC_, H2_, 12);
    lstm_enc_k<<<64, 768, 0, stream>>>(Xf, Xb, Whf, Whb, enc, pairsF, pairsB,
                                       pairsD, c0);
    lstm_dec_k<<<128, 768, 0, stream>>>(Xd, dWh, Hn, pairsD, c0);
    gemm_bias_k<<<dim3(H2_ / BN, 1), 256, 0, stream>>>(Hn, aW, nullptr, Amat,
                                                       T_, H2_, H2_, 0, 1);
    score_k<<<T_, 256, 0, stream>>>(Amat, enc, out);
}